// Round 1
// baseline (230.325 us; speedup 1.0000x reference)
//
#include <hip/hip_runtime.h>
#include <hip/hip_bf16.h>
#include <stdint.h>

// GCN on MI355X. ALL I/O IS FLOAT32.
//   out0 = relu( (D^-1/2 A D^-1/2) @ (graph @ W) + bias )   [16,4096,64] fp32
//   out1 = adj (verbatim fp32 copy)                          [4096,4096] fp32
// r1: k_gemm rewritten as 256x256 tile, 512 threads (8 waves 2x4), BK=64,
// double-buffered 128KiB LDS, 4-phase schedule: stage tile t+1 at top of
// iter t (freed buffer), vmcnt(0) deferred to end of phase 4 (~2.5 phases
// of MFMA latency cover vs 0 in the old stage->drain structure), raw
// s_barrier per phase, setprio(1) around MFMA clusters. Swizzle + fragment
// layout + store epilogue identical to the previously verified kernel.

typedef __bf16 bf16;
typedef __bf16 bf16x4 __attribute__((ext_vector_type(4)));
typedef __bf16 bf16x8 __attribute__((ext_vector_type(8)));
typedef float f32x4 __attribute__((ext_vector_type(4)));

#define NN 4096
#define BATCH 16
#define FD 64
#define CDIM 1024   // BATCH*FD

// ---------- Kernel 1: adj -> bf16 + rowsum -> dsq ; optional fused out1 copy ----------
__global__ __launch_bounds__(256) void k_prep(const float* __restrict__ adj,
                                              bf16* __restrict__ adjb,
                                              float* __restrict__ dsq,
                                              float4* __restrict__ out1,
                                              int do_copy) {
    int row = blockIdx.x;
    const float4* p = (const float4*)(adj + (size_t)row * NN);  // 1024 x float4
    uint4* q = (uint4*)(adjb + (size_t)row * NN);               // 512 x (8 bf16)
    float4* o = out1 + (size_t)row * (NN / 4);
    float s = 0.f;
    for (int j = threadIdx.x; j < 512; j += 256) {
        float4 a = p[2 * j], b = p[2 * j + 1];
        if (do_copy) { o[2 * j] = a; o[2 * j + 1] = b; }
        bf16x8 h;
        h[0] = (bf16)a.x; h[1] = (bf16)a.y; h[2] = (bf16)a.z; h[3] = (bf16)a.w;
        h[4] = (bf16)b.x; h[5] = (bf16)b.y; h[6] = (bf16)b.z; h[7] = (bf16)b.w;
        q[j] = __builtin_bit_cast(uint4, h);
        s += a.x + a.y + a.z + a.w + b.x + b.y + b.z + b.w;
    }
    #pragma unroll
    for (int off = 32; off > 0; off >>= 1) s += __shfl_down(s, off, 64);
    __shared__ float red[4];
    int lane = threadIdx.x & 63, wv = threadIdx.x >> 6;
    if (lane == 0) red[wv] = s;
    __syncthreads();
    if (threadIdx.x == 0) {
        float t = red[0] + red[1] + red[2] + red[3];
        if (t == 0.f) t = 1.f;              // isolated-node guard (ref semantics)
        dsq[row] = 1.0f / sqrtf(t);
    }
}

// ---------- Kernel 2: spT[c=b*64+o][m] = dsq[m] * sum_i graph[b,m,i]*W[i,o] ----------
__global__ __launch_bounds__(256) void k_support(const float* __restrict__ graph,
                                                 const float* __restrict__ weight,
                                                 const float* __restrict__ dsq,
                                                 bf16* __restrict__ spT) {
    __shared__ float wT[64 * 64];           // wT[o*64+i]
    int tid = threadIdx.x;
    for (int idx = tid; idx < 4096; idx += 256) {
        int i = idx >> 6, o = idx & 63;
        wT[o * 64 + i] = weight[idx];
    }
    __syncthreads();
    int b = blockIdx.y;
    int m = blockIdx.x * 256 + tid;
    const float4* g4 = (const float4*)(graph + ((size_t)b * NN + m) * FD);
    float ds = dsq[m];
    float gr[64];
    #pragma unroll
    for (int j = 0; j < 16; j++) {
        float4 v = g4[j];
        gr[4 * j] = v.x * ds; gr[4 * j + 1] = v.y * ds;
        gr[4 * j + 2] = v.z * ds; gr[4 * j + 3] = v.w * ds;
    }
    bf16* outp = spT + m;
    for (int o = 0; o < 64; o++) {
        const float4* w4 = (const float4*)&wT[o * 64];
        float acc = 0.f;
        #pragma unroll
        for (int j = 0; j < 16; j++) {
            float4 wv = w4[j];
            acc += gr[4 * j] * wv.x + gr[4 * j + 1] * wv.y
                 + gr[4 * j + 2] * wv.z + gr[4 * j + 3] * wv.w;
        }
        outp[(size_t)(b * 64 + o) * NN] = (bf16)acc;
    }
}

// ---------- Kernel 3: part_z[n][c] = bf16( dsq[n] * sum_{chunk z} adjb[n][m]*spT[c][m] ) ----------
// grid (16, 4, nsplit), 512 threads. 256x256 tile, BK=64, 4-phase pipelined
// schedule with double-buffered LDS (128 KiB) and deferred vmcnt.
__global__ __launch_bounds__(512, 2) void k_gemm(const bf16* __restrict__ adjb,
                                                 const bf16* __restrict__ spT,
                                                 const float* __restrict__ dsq,
                                                 bf16* __restrict__ part,
                                                 int kchunk) {
    __shared__ bf16x8 lds_a[2][2048];  // A: 256 rows x 64 k per buf; chunk g=(row*8+sub)
    __shared__ bf16x8 lds_b[2][2048];  //   holds global sub' = sub ^ (row&7)
    const int tid = threadIdx.x;
    const int lane = tid & 63;
    const int w = tid >> 6;                 // 0..7
    const int wr = w >> 2, wc = w & 3;      // 2x4 wave grid; per-wave out 128x64
    const int r = lane & 15, qo = lane >> 4;
    const int n0 = blockIdx.x * 256;
    const int c0 = blockIdx.y * 256;
    const size_t kbase = (size_t)blockIdx.z * kchunk;
    const int nt = kchunk >> 6;
    bf16* __restrict__ pp = part + (size_t)blockIdx.z * NN * CDIM;

    // Staging pointers (global-side swizzle; LDS writes stay linear).
    // Load instr j covers chunks [j*512, +512); lane supplies the global
    // address of the swizzled sub-chunk that lands at its slot.
    const bf16* gA[4]; const bf16* gB[4];
    #pragma unroll
    for (int j = 0; j < 4; j++) {
        int g = j * 512 + tid;
        int row = g >> 3;
        int sub = (g & 7) ^ (row & 7);      // global-side swizzle
        gA[j] = adjb + (size_t)(n0 + row) * NN + kbase + sub * 8;
        gB[j] = spT  + (size_t)(c0 + row) * NN + kbase + sub * 8;
    }

    // Fragment addressing: chunk = row*8 + (kchunkidx ^ (row&7)); row&7 == r&7.
    const int rowA0 = wr * 128 + r;         // + mi*16
    const int rowB0 = wc * 64 + r;          // + ni*16
    const int cc  = qo ^ (r & 7);           // k-half 0 xor'd chunk index
    const int aoff  = rowA0 * 8 + cc;
    const int aoff4 = rowA0 * 8 + (cc ^ 4);
    const int boff  = rowB0 * 8 + cc;
    const int boff4 = rowB0 * 8 + (cc ^ 4);

    f32x4 ac[8][4];
    #pragma unroll
    for (int i = 0; i < 8; i++)
        #pragma unroll
        for (int j = 0; j < 4; j++)
            ac[i][j] = (f32x4){0.f, 0.f, 0.f, 0.f};

    bf16x8 a_[4][2];    // 4 m-frags x 2 k-halves (reused for mh=0/1)
    bf16x8 b_[2][2];    // 2 n-frags x 2 k-halves (reused for np=0/1)

#define GLL(gp, lp) __builtin_amdgcn_global_load_lds( \
        (const __attribute__((address_space(1))) void*)(gp), \
        (__attribute__((address_space(3))) void*)(lp), 16, 0, 0)

#define LDA(mh) { _Pragma("unroll") \
    for (int mi = 0; mi < 4; mi++) { \
        a_[mi][0] = fa[aoff  + (mh) * 512 + mi * 128]; \
        a_[mi][1] = fa[aoff4 + (mh) * 512 + mi * 128]; \
    } }

#define LDB(np) { _Pragma("unroll") \
    for (int u = 0; u < 2; u++) { \
        b_[u][0] = fb[boff  + ((np) * 2 + u) * 128]; \
        b_[u][1] = fb[boff4 + ((np) * 2 + u) * 128]; \
    } }

#define MM(mh, np) { _Pragma("unroll") \
    for (int mi = 0; mi < 4; mi++) { \
        _Pragma("unroll") \
        for (int u = 0; u < 2; u++) { \
            ac[(mh)*4+mi][(np)*2+u] = __builtin_amdgcn_mfma_f32_16x16x32_bf16( \
                a_[mi][0], b_[u][0], ac[(mh)*4+mi][(np)*2+u], 0, 0, 0); \
            ac[(mh)*4+mi][(np)*2+u] = __builtin_amdgcn_mfma_f32_16x16x32_bf16( \
                a_[mi][1], b_[u][1], ac[(mh)*4+mi][(np)*2+u], 0, 0, 0); \
        } } }

    // Prologue: stage tile 0 into buf 0, drain, barrier.
    #pragma unroll
    for (int j = 0; j < 4; j++) {
        GLL(gA[j], &lds_a[0][j * 512 + (w << 6)]);
        GLL(gB[j], &lds_b[0][j * 512 + (w << 6)]);
    }
    asm volatile("s_waitcnt vmcnt(0)" ::: "memory");
    __builtin_amdgcn_s_barrier();
    asm volatile("" ::: "memory");

    for (int t = 0; t < nt; t++) {
        const bf16x8* fa = lds_a[t & 1];
        const bf16x8* fb = lds_b[t & 1];
        bf16x8* sa = lds_a[(t + 1) & 1];     // freed by iter t-1's end barrier
        bf16x8* sb = lds_b[(t + 1) & 1];
        const int toff = (t + 1) * 64;
        const bool st = (t + 1 < nt);

        // ---- Phase 1: A(mi 0-3) + B(ni 0-1); issue A-stage for tile t+1
        LDA(0); LDB(0);
        if (st) {
            #pragma unroll
            for (int j = 0; j < 4; j++) GLL(gA[j] + toff, &sa[j * 512 + (w << 6)]);
        }
        __builtin_amdgcn_s_barrier();
        __builtin_amdgcn_s_setprio(1);
        MM(0, 0);
        __builtin_amdgcn_s_setprio(0);
        __builtin_amdgcn_s_barrier();

        // ---- Phase 2: B(ni 2-3); issue B-stage for tile t+1
        LDB(1);
        if (st) {
            #pragma unroll
            for (int j = 0; j < 4; j++) GLL(gB[j] + toff, &sb[j * 512 + (w << 6)]);
        }
        __builtin_amdgcn_s_barrier();
        __builtin_amdgcn_s_setprio(1);
        MM(0, 1);
        __builtin_amdgcn_s_setprio(0);
        __builtin_amdgcn_s_barrier();

        // ---- Phase 3: A(mi 4-7)
        LDA(1);
        __builtin_amdgcn_s_barrier();
        __builtin_amdgcn_s_setprio(1);
        MM(1, 1);
        __builtin_amdgcn_s_setprio(0);
        __builtin_amdgcn_s_barrier();

        // ---- Phase 4: B(ni 0-1) again; deferred wait for tile t+1's loads
        LDB(0);
        __builtin_amdgcn_s_barrier();
        __builtin_amdgcn_s_setprio(1);
        MM(1, 0);
        __builtin_amdgcn_s_setprio(0);
        if (st) asm volatile("s_waitcnt vmcnt(0)" ::: "memory");
        __builtin_amdgcn_s_barrier();
        asm volatile("" ::: "memory");
    }

#undef GLL
#undef LDA
#undef LDB
#undef MM

    // Store bf16 partial with dsq[n] folded.
    // n = n0 + wr*128 + mi*16 + qo*4 + rr ; c = c0 + wc*64 + ni*16 + r
    #pragma unroll
    for (int mi = 0; mi < 8; mi++) {
        float dn[4];
        #pragma unroll
        for (int rr = 0; rr < 4; rr++)
            dn[rr] = dsq[n0 + wr * 128 + mi * 16 + qo * 4 + rr];
        #pragma unroll
        for (int ni = 0; ni < 4; ni++) {
            int c = c0 + wc * 64 + ni * 16 + r;
            #pragma unroll
            for (int rr = 0; rr < 4; rr++) {
                int n = n0 + wr * 128 + mi * 16 + qo * 4 + rr;
                pp[(size_t)n * CDIM + c] = (bf16)(dn[rr] * ac[mi][ni][rr]);
            }
        }
    }
}

// ---------- Kernel 4: out0[b,n,o] = relu(sum_z part_z[n][b*64+o] + bias[o]) ----------
__global__ __launch_bounds__(256) void k_epi(const bf16* __restrict__ part,
                                             int nsplit,
                                             const float* __restrict__ bias,
                                             float4* __restrict__ out0) {
    int idx = blockIdx.x * 256 + threadIdx.x;       // 1,048,576 x (4 floats)
    int flat = idx * 4;
    int o4 = flat & 63;
    int n = (flat >> 6) & (NN - 1);
    int b = flat >> 18;                             // 4096*64 = 1<<18
    size_t off = (size_t)n * CDIM + b * 64 + o4;    // element offset, %4==0
    const size_t zstride = (size_t)NN * CDIM;
    float ax = 0.f, ay = 0.f, az = 0.f, aw = 0.f;
    for (int z = 0; z < nsplit; z++) {
        bf16x4 t = *(const bf16x4*)(part + off + z * zstride);
        ax += (float)t[0]; ay += (float)t[1]; az += (float)t[2]; aw += (float)t[3];
    }
    float4 bv = *(const float4*)(bias + o4);
    float4 r;
    r.x = fmaxf(ax + bv.x, 0.f);
    r.y = fmaxf(ay + bv.y, 0.f);
    r.z = fmaxf(az + bv.z, 0.f);
    r.w = fmaxf(aw + bv.w, 0.f);
    out0[idx] = r;
}

// ---------- Kernel 5: adj -> out1 fp32 copy (fallback path only, runs LAST) ----------
__global__ __launch_bounds__(256) void k_copy(const float4* __restrict__ src,
                                              float4* __restrict__ dst) {
    size_t i = (size_t)blockIdx.x * 256 + threadIdx.x;
    dst[i] = src[i];
}

extern "C" void kernel_launch(void* const* d_in, const int* in_sizes, int n_in,
                              void* d_out, int out_size, void* d_ws, size_t ws_size,
                              hipStream_t stream) {
    const float *graph = nullptr, *adj = nullptr, *weight = nullptr, *bias = nullptr;
    for (int i = 0; i < n_in; i++) {
        const float* p = (const float*)d_in[i];
        switch (in_sizes[i]) {
            case BATCH * NN * FD: graph  = p; break;   // 4,194,304
            case NN * NN:         adj    = p; break;   // 16,777,216
            case FD * FD:         weight = p; break;   // 4,096
            case FD:              bias   = p; break;   // 64
        }
    }

    float* out0 = (float*)d_out;                       // [16,4096,64] fp32 (16.8MB)
    float* out1 = out0 + (size_t)BATCH * NN * FD;      // [4096,4096] fp32 (67MB)

    const size_t SZ_ADJB = (size_t)NN * NN * 2;            // 32 MiB
    const size_t SZ_SPT  = (size_t)CDIM * NN * 2;          // 8 MiB
    const size_t SZ_DSQ  = (size_t)NN * 4;                 // 16 KiB
    const size_t SZ_PART = (size_t)NN * CDIM * 2;          // 8.4 MiB per split (bf16)

    bf16 *adjb, *spT, *part; float *dsq;
    int nsplit, do_copy_in_prep;
    if (ws_size >= SZ_ADJB + SZ_SPT + SZ_DSQ + 4 * SZ_PART) {
        nsplit = 4; do_copy_in_prep = 1;
        char* s = (char*)d_ws;
        adjb = (bf16*)s;
        spT  = (bf16*)(s + SZ_ADJB);
        dsq  = (float*)(s + SZ_ADJB + SZ_SPT);
        part = (bf16*)(s + SZ_ADJB + SZ_SPT + SZ_DSQ);
    } else if (ws_size >= SZ_ADJB + SZ_SPT + SZ_DSQ + 2 * SZ_PART) {
        nsplit = 2; do_copy_in_prep = 1;
        char* s = (char*)d_ws;
        adjb = (bf16*)s;
        spT  = (bf16*)(s + SZ_ADJB);
        dsq  = (float*)(s + SZ_ADJB + SZ_SPT);
        part = (bf16*)(s + SZ_ADJB + SZ_SPT + SZ_DSQ);
    } else {
        // Carve: out1 = [part 4x8.4MB | adjb 32MB] (~66MB of 67MB);
        //        out0 = [spT 8MB | dsq 16KB] (consumed before k_epi writes out0).
        nsplit = 4; do_copy_in_prep = 0;
        part = (bf16*)out1;
        adjb = (bf16*)((char*)out1 + 4 * SZ_PART);
        spT  = (bf16*)out0;
        dsq  = (float*)((char*)out0 + SZ_SPT);
    }
    const int kchunk = NN / nsplit;

    hipLaunchKernelGGL(k_prep, dim3(NN), dim3(256), 0, stream,
                       adj, adjb, dsq, (float4*)out1, do_copy_in_prep);
    hipLaunchKernelGGL(k_support, dim3(16, 16), dim3(256), 0, stream,
                       graph, weight, dsq, spT);
    hipLaunchKernelGGL(k_gemm, dim3(16, 4, nsplit), dim3(512), 0, stream,
                       adjb, spT, dsq, part, kchunk);
    hipLaunchKernelGGL(k_epi, dim3(4096), dim3(256), 0, stream,
                       part, nsplit, bias, (float4*)out0);
    if (!do_copy_in_prep) {
        hipLaunchKernelGGL(k_copy, dim3(16384), dim3(256), 0, stream,
                           (const float4*)adj, (float4*)out1);
    }
}